// Round 4
// baseline (270.453 us; speedup 1.0000x reference)
//
#include <hip/hip_runtime.h>
#include <cfloat>
#include <cstdint>

#define BATCH 2
#define NSEQ 2048
#define CIN 512
#define HEADS 8
#define DIM 64
#define HD 512
#define QKV3 1536

typedef short short8 __attribute__((ext_vector_type(8)));
typedef float f32x4 __attribute__((ext_vector_type(4)));
typedef unsigned short ushort_t;

__device__ __forceinline__ unsigned short f2bf(float f) {
    return (unsigned short)(__float_as_uint(f) >> 16);
}
__device__ __forceinline__ float bf2f(unsigned short h) {
    return __uint_as_float(((unsigned int)h) << 16);
}

// ---------- split + transpose weights: W[K][N] f32 -> WT[N][K] bf16 hi/lo ----
__global__ __launch_bounds__(256) void split_wT_kernel(
    const float* __restrict__ W, ushort_t* __restrict__ WTh,
    ushort_t* __restrict__ WTl, int K, int N)
{
    __shared__ float T[64][65];
    const int k0 = blockIdx.y * 64, n0 = blockIdx.x * 64;
    const int tid = threadIdx.x;
    #pragma unroll
    for (int i = 0; i < 4; ++i) {
        int c = tid + i * 256;
        int row = c >> 4, c4 = c & 15;
        *(float4*)&T[row][c4*4] = *(const float4*)(W + (size_t)(k0 + row) * N + n0 + c4*4);
    }
    __syncthreads();
    const int n = tid >> 2, kseg = tid & 3;
    short8 hh0, ll0, hh1, ll1;
    #pragma unroll
    for (int e = 0; e < 8; ++e) {
        float x0 = T[kseg*16 + e][n];
        unsigned short h0 = f2bf(x0);
        hh0[e] = (short)h0; ll0[e] = (short)f2bf(x0 - bf2f(h0));
        float x1 = T[kseg*16 + 8 + e][n];
        unsigned short h1 = f2bf(x1);
        hh1[e] = (short)h1; ll1[e] = (short)f2bf(x1 - bf2f(h1));
    }
    size_t o = (size_t)(n0 + n) * K + k0 + kseg * 16;
    *(short8*)(WTh + o)     = hh0;
    *(short8*)(WTh + o + 8) = hh1;
    *(short8*)(WTl + o)     = ll0;
    *(short8*)(WTl + o + 8) = ll1;
}

// ---------- split flat f32 array -> bf16 hi/lo --------------------------
__global__ __launch_bounds__(256) void split_f32_kernel(
    const float* __restrict__ X, ushort_t* __restrict__ Xh,
    ushort_t* __restrict__ Xl)
{
    int i = blockIdx.x * 256 + threadIdx.x;   // 8-elem group index
    float4 a = ((const float4*)X)[i*2];
    float4 c = ((const float4*)X)[i*2 + 1];
    float v[8] = {a.x,a.y,a.z,a.w,c.x,c.y,c.z,c.w};
    short8 hh, ll;
    #pragma unroll
    for (int e = 0; e < 8; ++e) {
        unsigned short hi = f2bf(v[e]);
        hh[e] = (short)hi;
        ll[e] = (short)f2bf(v[e] - bf2f(hi));
    }
    *(short8*)(Xh + (size_t)i*8) = hh;
    *(short8*)(Xl + (size_t)i*8) = ll;
}

// ---------- split-bf16 MFMA GEMM: C = A(h/l)[M][K] @ BT(h/l)[N][K] ------
// BM=128 BN=64 BK=64, 4 waves, wave-tile 64x32
__global__ __launch_bounds__(256, 2) void gemm_bf16_kernel(
    const ushort_t* __restrict__ Ah, const ushort_t* __restrict__ Al,
    const ushort_t* __restrict__ BTh, const ushort_t* __restrict__ BTl,
    float* __restrict__ C, int M, int N, int K)
{
    __shared__ ushort_t Ash[128][72], Asl[128][72];
    __shared__ ushort_t Bsh[64][72],  Bsl[64][72];
    const int bm = blockIdx.y * 128, bn = blockIdx.x * 64;
    const int tid = threadIdx.x;
    const int wave = tid >> 6, lane = tid & 63;
    const int lg = lane >> 4, lm = lane & 15;
    const int wm = wave >> 1, wn = wave & 1;
    const int arow = tid >> 3, aseg = tid & 7;

    f32x4 acc[4][2];
    #pragma unroll
    for (int mf = 0; mf < 4; ++mf)
        #pragma unroll
        for (int nf = 0; nf < 2; ++nf) acc[mf][nf] = (f32x4){0.f,0.f,0.f,0.f};

    uint4 arh[4], arl[4], brh[2], brl[2];
    const int nkt = K >> 6;

    #define G_ISSUE(K0)                                                        \
        { _Pragma("unroll")                                                    \
          for (int i = 0; i < 4; ++i) {                                        \
            size_t ao = (size_t)(bm + arow + 32*i) * K + (K0) + aseg*8;        \
            arh[i] = *(const uint4*)(Ah + ao);                                 \
            arl[i] = *(const uint4*)(Al + ao);                                 \
          }                                                                    \
          _Pragma("unroll")                                                    \
          for (int i = 0; i < 2; ++i) {                                        \
            size_t bo = (size_t)(bn + arow + 32*i) * K + (K0) + aseg*8;        \
            brh[i] = *(const uint4*)(BTh + bo);                                \
            brl[i] = *(const uint4*)(BTl + bo);                                \
          } }

    G_ISSUE(0)
    for (int kt = 0; kt < nkt; ++kt) {
        __syncthreads();
        #pragma unroll
        for (int i = 0; i < 4; ++i) {
            *(uint4*)&Ash[arow + 32*i][aseg*8] = arh[i];
            *(uint4*)&Asl[arow + 32*i][aseg*8] = arl[i];
        }
        #pragma unroll
        for (int i = 0; i < 2; ++i) {
            *(uint4*)&Bsh[arow + 32*i][aseg*8] = brh[i];
            *(uint4*)&Bsl[arow + 32*i][aseg*8] = brl[i];
        }
        if (kt + 1 < nkt) G_ISSUE((kt + 1) * 64)
        __syncthreads();
        #pragma unroll
        for (int ks = 0; ks < 2; ++ks) {
            short8 afh[4], afl[4], bfh[2], bfl[2];
            #pragma unroll
            for (int mf = 0; mf < 4; ++mf) {
                afh[mf] = *(const short8*)&Ash[wm*64 + mf*16 + lm][ks*32 + lg*8];
                afl[mf] = *(const short8*)&Asl[wm*64 + mf*16 + lm][ks*32 + lg*8];
            }
            #pragma unroll
            for (int nf = 0; nf < 2; ++nf) {
                bfh[nf] = *(const short8*)&Bsh[wn*32 + nf*16 + lm][ks*32 + lg*8];
                bfl[nf] = *(const short8*)&Bsl[wn*32 + nf*16 + lm][ks*32 + lg*8];
            }
            #pragma unroll
            for (int mf = 0; mf < 4; ++mf)
                #pragma unroll
                for (int nf = 0; nf < 2; ++nf) {
                    acc[mf][nf] = __builtin_amdgcn_mfma_f32_16x16x32_bf16(afh[mf], bfh[nf], acc[mf][nf], 0, 0, 0);
                    acc[mf][nf] = __builtin_amdgcn_mfma_f32_16x16x32_bf16(afh[mf], bfl[nf], acc[mf][nf], 0, 0, 0);
                    acc[mf][nf] = __builtin_amdgcn_mfma_f32_16x16x32_bf16(afl[mf], bfh[nf], acc[mf][nf], 0, 0, 0);
                }
        }
    }
    #pragma unroll
    for (int mf = 0; mf < 4; ++mf)
        #pragma unroll
        for (int nf = 0; nf < 2; ++nf)
            #pragma unroll
            for (int r = 0; r < 4; ++r)
                C[(size_t)(bm + wm*64 + mf*16 + lg*4 + r) * N + bn + wn*32 + nf*16 + lm]
                    = acc[mf][nf][r];
    #undef G_ISSUE
}

// ------- scatter qkv_lin -> Qh/Ql/Kh/Kl bf16 [B,H,N,D], l2norm(q,k) -----
__global__ __launch_bounds__(256) void scatter_norm_kernel(
    const float* __restrict__ qkv,
    ushort_t* __restrict__ Qh, ushort_t* __restrict__ Ql,
    ushort_t* __restrict__ Kh, ushort_t* __restrict__ Kl)
{
    int gid = blockIdx.x * 256 + threadIdx.x;
    int wid = gid >> 6;
    int lane = threadIdx.x & 63;
    int h = wid & 7;
    int row = wid >> 3;
    const float* p = qkv + (size_t)row * QKV3 + h * 192 + lane * 3;
    float q = p[0], k = p[1];
    float nq = q * q, nk = k * k;
    #pragma unroll
    for (int off = 32; off > 0; off >>= 1) {
        nq += __shfl_xor(nq, off);
        nk += __shfl_xor(nk, off);
    }
    float rq = 1.f / fmaxf(sqrtf(nq), 1e-12f);
    float rk = 1.f / fmaxf(sqrtf(nk), 1e-12f);
    q *= rq; k *= rk;
    int b = row >> 11, n = row & (NSEQ - 1);
    size_t o = (((size_t)(b * HEADS + h)) * NSEQ + n) * DIM + lane;
    unsigned short qhi = f2bf(q), khi = f2bf(k);
    Qh[o] = qhi; Ql[o] = f2bf(q - bf2f(qhi));
    Kh[o] = khi; Kl[o] = f2bf(k - bf2f(khi));
}

// ------- V transpose: qkv_lin -> Vt_hi/Vt_lo bf16 [BH][D][N], j-PERMUTED -
// within each 32-col block, position p holds j = perm(p):
// j[5]=p[5], j[4]=p[2], j[3:2]=p[4:3], j[1:0]=p[1:0]
__global__ __launch_bounds__(256) void vtrans_kernel(
    const float* __restrict__ qkv,
    ushort_t* __restrict__ Vth, ushort_t* __restrict__ Vtl)
{
    __shared__ ushort_t VhS[64][72], VlS[64][72];
    const int id = blockIdx.x;
    const int bh = id >> 5, nt = id & 31;
    const int b = bh >> 3, h = bh & 7;
    const int n0 = nt * 64;
    const int tid = threadIdx.x;
    {
        int j = tid >> 2, dseg = tid & 3;
        const float* src = qkv + ((size_t)(b * NSEQ + n0 + j)) * QKV3
                         + h * 192 + dseg * 48 + 2;
        #pragma unroll
        for (int e = 0; e < 16; ++e) {
            float v = src[e * 3];
            unsigned short hi = f2bf(v);
            VhS[dseg*16 + e][j] = hi;
            VlS[dseg*16 + e][j] = f2bf(v - bf2f(hi));
        }
    }
    __syncthreads();
    {
        int d = tid >> 2, seg = tid & 3;
        ushort_t th[16], tl[16];
        #pragma unroll
        for (int t = 0; t < 16; ++t) {
            int p = seg * 16 + t;
            int src = (p & 35) | ((p & 4) << 2) | ((p >> 1) & 12);
            th[t] = VhS[d][src];
            tl[t] = VlS[d][src];
        }
        size_t o = ((size_t)(bh * DIM + d)) * NSEQ + n0 + seg * 16;
        *(uint4*)(Vth + o)     = *(uint4*)&th[0];
        *(uint4*)(Vth + o + 8) = *(uint4*)&th[8];
        *(uint4*)(Vtl + o)     = *(uint4*)&tl[0];
        *(uint4*)(Vtl + o + 8) = *(uint4*)&tl[8];
    }
}

// ---------------- MFMA flash attention v4: swapped QK^T, in-reg softmax --
// Q-tile 128 (4 waves x 32 rows), KV-tile 64 dbuf, j-split 2, grid 512
__global__ __launch_bounds__(256, 2) void attn_mfma_kernel(
    const ushort_t* __restrict__ Qh, const ushort_t* __restrict__ Ql,
    const ushort_t* __restrict__ Kh, const ushort_t* __restrict__ Kl,
    const ushort_t* __restrict__ Vth, const ushort_t* __restrict__ Vtl,
    const float* __restrict__ bias, const float* __restrict__ temp_p,
    const uint8_t* __restrict__ mask, float* __restrict__ Opart,
    float* __restrict__ Ml)
{
    __shared__ ushort_t KsH[2][64][72], KsL[2][64][72];   // [buf][j][d]
    __shared__ ushort_t VsH[2][64][72], VsL[2][64][72];   // [buf][d][j-perm]

    const int id = blockIdx.x;
    const int h = id & 7;                 // XCD-grouped
    const int rest = id >> 3;
    const int js = rest & 1;
    const int qt = (rest >> 1) & 15;
    const int b = rest >> 5;
    const int bh = b * 8 + h;
    const int i0 = qt * 128;
    const int tid = threadIdx.x;
    const int wave = tid >> 6, lane = tid & 63;
    const int lg = lane >> 4, lm = lane & 15;
    const int qbase = i0 + wave * 32;
    const float temp = *temp_p;
    const int srow = tid >> 3, sseg = tid & 7;

    // Q fragments (now the B-operand of swapped QK^T; same data layout)
    short8 qfh[2][2], qfl[2][2];
    #pragma unroll
    for (int m = 0; m < 2; ++m) {
        size_t qo = ((size_t)(bh * NSEQ + qbase + 16*m + lm)) * DIM + lg * 8;
        qfh[m][0] = *(const short8*)(Qh + qo);
        qfh[m][1] = *(const short8*)(Qh + qo + 32);
        qfl[m][0] = *(const short8*)(Ql + qo);
        qfl[m][1] = *(const short8*)(Ql + qo + 32);
    }
    bool rowm[2];
    rowm[0] = mask[(size_t)b * NSEQ + qbase + lm] != 0;
    rowm[1] = mask[(size_t)b * NSEQ + qbase + 16 + lm] != 0;

    float m_r[2] = {-FLT_MAX, -FLT_MAX};
    float l_r[2] = {0.f, 0.f};
    f32x4 oa[2][4];
    #pragma unroll
    for (int m = 0; m < 2; ++m)
        #pragma unroll
        for (int dt = 0; dt < 4; ++dt) oa[m][dt] = (f32x4){0.f,0.f,0.f,0.f};

    uint4 skh[2], skl[2], svh[2], svl[2];
    const int NT = (NSEQ / 2) / 64;
    const int jbase = js * (NSEQ / 2);

    #define A_ISSUE(J0)                                                           \
        { _Pragma("unroll")                                                       \
          for (int i = 0; i < 2; ++i) {                                           \
            size_t gk = ((size_t)(bh * NSEQ) + (J0) + srow + 32*i) * DIM + sseg*8;\
            size_t gv = ((size_t)(bh * DIM)  + srow + 32*i) * NSEQ + (J0) + sseg*8;\
            skh[i] = *(const uint4*)(Kh  + gk);                                   \
            skl[i] = *(const uint4*)(Kl  + gk);                                   \
            svh[i] = *(const uint4*)(Vth + gv);                                   \
            svl[i] = *(const uint4*)(Vtl + gv);                                   \
          } }

    A_ISSUE(jbase)
    #pragma unroll
    for (int i = 0; i < 2; ++i) {
        *(uint4*)&KsH[0][srow + 32*i][sseg*8] = skh[i];
        *(uint4*)&KsL[0][srow + 32*i][sseg*8] = skl[i];
        *(uint4*)&VsH[0][srow + 32*i][sseg*8] = svh[i];
        *(uint4*)&VsL[0][srow + 32*i][sseg*8] = svl[i];
    }
    A_ISSUE(jbase + 64)
    __syncthreads();

    #pragma unroll 1
    for (int t = 0; t < NT; ++t) {
        const int j0 = jbase + t * 64;
        const int cur = t & 1;

        // column mask as a wave ballot (bit j = masked)
        unsigned long long bal =
            __ballot(mask[(size_t)b * NSEQ + j0 + lane] != 0);
        // bias: float4 per (m,jt) — r components contiguous
        float4 bb[2][4];
        #pragma unroll
        for (int m = 0; m < 2; ++m)
            #pragma unroll
            for (int jt = 0; jt < 4; ++jt)
                bb[m][jt] = *(const float4*)(bias
                    + ((size_t)h * NSEQ + qbase + 16*m + lm) * NSEQ
                    + j0 + jt*16 + lg*4);

        // ---- S^T = K.Q via swapped split MFMA ----
        // lane holds S[q=lm][k=jt*16+lg*4+r]
        f32x4 sac[2][4];
        #pragma unroll
        for (int m = 0; m < 2; ++m)
            #pragma unroll
            for (int jt = 0; jt < 4; ++jt) sac[m][jt] = (f32x4){0.f,0.f,0.f,0.f};
        #pragma unroll
        for (int jt = 0; jt < 4; ++jt)
            #pragma unroll
            for (int ks = 0; ks < 2; ++ks) {
                short8 kbh = *(const short8*)(&KsH[cur][jt*16 + lm][ks*32 + lg*8]);
                short8 kbl = *(const short8*)(&KsL[cur][jt*16 + lm][ks*32 + lg*8]);
                #pragma unroll
                for (int m = 0; m < 2; ++m) {
                    sac[m][jt] = __builtin_amdgcn_mfma_f32_16x16x32_bf16(kbh, qfh[m][ks], sac[m][jt], 0, 0, 0);
                    sac[m][jt] = __builtin_amdgcn_mfma_f32_16x16x32_bf16(kbh, qfl[m][ks], sac[m][jt], 0, 0, 0);
                    sac[m][jt] = __builtin_amdgcn_mfma_f32_16x16x32_bf16(kbl, qfh[m][ks], sac[m][jt], 0, 0, 0);
                }
            }

        // ---- in-register online softmax (q-row = lm, lane-local) ----
        short8 pah[2][2], pal[2][2];
        float scl[2];
        #pragma unroll
        for (int m = 0; m < 2; ++m) {
            float sv[4][4];
            #pragma unroll
            for (int jt = 0; jt < 4; ++jt) {
                unsigned int nib = (unsigned int)(bal >> (jt*16 + lg*4)) & 0xFu;
                #pragma unroll
                for (int r = 0; r < 4; ++r) {
                    bool dead = rowm[m] || ((nib >> r) & 1u);
                    float bv = (r == 0) ? bb[m][jt].x : (r == 1) ? bb[m][jt].y
                             : (r == 2) ? bb[m][jt].z : bb[m][jt].w;
                    sv[jt][r] = dead ? -FLT_MAX : fmaf(sac[m][jt][r], temp, bv);
                }
            }
            float mx = sv[0][0];
            #pragma unroll
            for (int jt = 0; jt < 4; ++jt)
                #pragma unroll
                for (int r = 0; r < 4; ++r) mx = fmaxf(mx, sv[jt][r]);
            mx = fmaxf(mx, __shfl_xor(mx, 16));
            mx = fmaxf(mx, __shfl_xor(mx, 32));
            float mn = fmaxf(m_r[m], mx);
            scl[m] = __expf(m_r[m] - mn);
            m_r[m] = mn;
            float rs = 0.f;
            #pragma unroll
            for (int jt = 0; jt < 4; ++jt)
                #pragma unroll
                for (int r = 0; r < 4; ++r) {
                    float pf = __expf(sv[jt][r] - mn);
                    rs += pf;
                    unsigned short hi = f2bf(pf);
                    pah[m][jt >> 1][(jt & 1)*4 + r] = (short)hi;
                    pal[m][jt >> 1][(jt & 1)*4 + r] = (short)f2bf(pf - bf2f(hi));
                }
            rs += __shfl_xor(rs, 16);
            rs += __shfl_xor(rs, 32);
            l_r[m] = l_r[m] * scl[m] + rs;
        }
        // rescale O: need scl for q=lg*4+r (held by lane lg*4+r)
        #pragma unroll
        for (int m = 0; m < 2; ++m)
            #pragma unroll
            for (int r = 0; r < 4; ++r) {
                float sq = __shfl(scl[m], lg*4 + r);
                #pragma unroll
                for (int dt = 0; dt < 4; ++dt) oa[m][dt][r] *= sq;
            }

        // stage next tile into the other buffer; issue t+2 loads
        if (t + 1 < NT) {
            #pragma unroll
            for (int i = 0; i < 2; ++i) {
                *(uint4*)&KsH[cur^1][srow + 32*i][sseg*8] = skh[i];
                *(uint4*)&KsL[cur^1][srow + 32*i][sseg*8] = skl[i];
                *(uint4*)&VsH[cur^1][srow + 32*i][sseg*8] = svh[i];
                *(uint4*)&VsL[cur^1][srow + 32*i][sseg*8] = svl[i];
            }
            if (t + 2 < NT) A_ISSUE(j0 + 128)
        }

        // ---- O += P.V (P A-frag in registers, V pre-permuted) ----
        #pragma unroll
        for (int ks = 0; ks < 2; ++ks)
            #pragma unroll
            for (int dt = 0; dt < 4; ++dt) {
                short8 vbh = *(const short8*)(&VsH[cur][dt*16 + lm][ks*32 + lg*8]);
                short8 vbl = *(const short8*)(&VsL[cur][dt*16 + lm][ks*32 + lg*8]);
                #pragma unroll
                for (int m = 0; m < 2; ++m) {
                    oa[m][dt] = __builtin_amdgcn_mfma_f32_16x16x32_bf16(pah[m][ks], vbh, oa[m][dt], 0, 0, 0);
                    oa[m][dt] = __builtin_amdgcn_mfma_f32_16x16x32_bf16(pah[m][ks], vbl, oa[m][dt], 0, 0, 0);
                    oa[m][dt] = __builtin_amdgcn_mfma_f32_16x16x32_bf16(pal[m][ks], vbh, oa[m][dt], 0, 0, 0);
                }
            }
        __syncthreads();
    }
    #undef A_ISSUE

    // ---- epilogue: unnormalized partials + (m,l) ----
    #pragma unroll
    for (int m = 0; m < 2; ++m)
        #pragma unroll
        for (int dt = 0; dt < 4; ++dt)
            #pragma unroll
            for (int r = 0; r < 4; ++r)
                Opart[((size_t)(js*16 + bh) * NSEQ + qbase + 16*m + lg*4 + r) * 64
                      + dt*16 + lm] = oa[m][dt][r];
    if (lane < 16) {
        #pragma unroll
        for (int m = 0; m < 2; ++m) {
            size_t mi = ((size_t)(js*16 + bh) * NSEQ + qbase + 16*m + lm) * 2;
            Ml[mi]     = m_r[m];
            Ml[mi + 1] = l_r[m];
        }
    }
}

// ------- merge 2 j-split partials -> AO bf16 hi/lo [M][HD] --------------
__global__ __launch_bounds__(256) void merge_kernel(
    const float* __restrict__ Opart, const float* __restrict__ Ml,
    ushort_t* __restrict__ AOh, ushort_t* __restrict__ AOl)
{
    int row = blockIdx.x * 4 + (threadIdx.x >> 6);
    int d = threadIdx.x & 63;
    int bh = row >> 11, n = row & (NSEQ - 1);
    int bq = bh >> 3, hq = bh & 7;
    size_t i1 = (size_t)bh * NSEQ + n;
    size_t i2 = (size_t)(16 + bh) * NSEQ + n;
    float m1 = Ml[i1*2], l1 = Ml[i1*2 + 1];
    float m2 = Ml[i2*2], l2 = Ml[i2*2 + 1];
    float mm = fmaxf(m1, m2);
    float w1 = __expf(m1 - mm), w2 = __expf(m2 - mm);
    float l = l1 * w1 + l2 * w2;
    float o = (Opart[i1*64 + d] * w1 + Opart[i2*64 + d] * w2) / l;
    size_t oi = ((size_t)(bq * NSEQ + n)) * HD + hq * DIM + d;
    unsigned short hi = f2bf(o);
    AOh[oi] = hi;
    AOl[oi] = f2bf(o - bf2f(hi));
}

extern "C" void kernel_launch(void* const* d_in, const int* in_sizes, int n_in,
                              void* d_out, int out_size, void* d_ws, size_t ws_size,
                              hipStream_t stream)
{
    const float*   x        = (const float*)d_in[0];
    const float*   w_qkv    = (const float*)d_in[1];
    const float*   w_out    = (const float*)d_in[2];
    const float*   pos_bias = (const float*)d_in[3];
    const float*   temp     = (const float*)d_in[4];
    const uint8_t* mask     = (const uint8_t*)d_in[5];
    float* out = (float*)d_out;

    const int M = BATCH * NSEQ;                        // 4096
    const size_t NE = (size_t)BATCH * HEADS * NSEQ * DIM;  // 2,097,152
    char* ws = (char*)d_ws;

    // region 0 (25.2 MB): qkv_lin, later reused for Opart + Ml
    float* qkv_lin = (float*)ws;
    float* OpartP  = (float*)ws;                                 // 16.8 MB
    float* MlP     = (float*)(ws + (size_t)2*16*NSEQ*64*4);      // 1 MB
    size_t off = (size_t)M * QKV3 * 4;
    // region 1 (4.2 MB): transposed/split weights
    ushort_t* WqkvTh = (ushort_t*)(ws + off); off += (size_t)QKV3 * CIN * 2;
    ushort_t* WqkvTl = (ushort_t*)(ws + off); off += (size_t)QKV3 * CIN * 2;
    ushort_t* WoutTh = (ushort_t*)(ws + off); off += (size_t)HD * CIN * 2;
    ushort_t* WoutTl = (ushort_t*)(ws + off); off += (size_t)HD * CIN * 2;
    // region 2 (25.2 MB): time-multiplexed
    //   phase A: xh,xl (first 2 slots)          -- input to qkv GEMM
    //   phase B: Qh,Ql,Kh,Kl,Vth,Vtl            -- attention operands
    //   phase C: AOh,AOl (first 2 slots)        -- merge output / out-proj A
    char* reg2 = ws + off;
    ushort_t* Qh  = (ushort_t*)reg2;
    ushort_t* Ql  = Qh + NE;
    ushort_t* Kh  = Ql + NE;
    ushort_t* Kl  = Kh + NE;
    ushort_t* Vth = Kl + NE;
    ushort_t* Vtl = Vth + NE;
    ushort_t* xh  = Qh, *xl = Ql;     // phase A aliases
    ushort_t* AOh = Qh, *AOl = Ql;    // phase C aliases

    // 1. weight split+transpose
    split_wT_kernel<<<dim3(QKV3/64, CIN/64), 256, 0, stream>>>(w_qkv, WqkvTh, WqkvTl, CIN, QKV3);
    split_wT_kernel<<<dim3(HD/64,  CIN/64), 256, 0, stream>>>(w_out, WoutTh, WoutTl, CIN, HD);
    // 2. split x -> bf16 hi/lo
    split_f32_kernel<<<dim3((M * CIN) / (256 * 8)), 256, 0, stream>>>(x, xh, xl);
    // 3. qkv projection (MFMA split, bf16 A)
    gemm_bf16_kernel<<<dim3(QKV3/64, M/128), 256, 0, stream>>>(
        xh, xl, WqkvTh, WqkvTl, qkv_lin, M, QKV3, CIN);
    // 4. l2norm + bf16 hi/lo split Q,K   (overwrites xh/xl — GEMM done)
    scatter_norm_kernel<<<dim3(M * HEADS / 4), 256, 0, stream>>>(qkv_lin, Qh, Ql, Kh, Kl);
    // 5. V transpose (j-permuted for PV fragment layout)
    vtrans_kernel<<<dim3(BATCH * HEADS * (NSEQ/64)), 256, 0, stream>>>(qkv_lin, Vth, Vtl);
    // 6. attention (j-split 2)  (Opart/Ml overwrite qkv_lin — dead now)
    attn_mfma_kernel<<<dim3(512), 256, 0, stream>>>(
        Qh, Ql, Kh, Kl, Vth, Vtl, pos_bias, temp, mask, OpartP, MlP);
    // 7. merge partials -> AO bf16 hi/lo (overwrites Qh/Ql — dead now)
    merge_kernel<<<dim3(M * HEADS / 4), 256, 0, stream>>>(OpartP, MlP, AOh, AOl);
    // 8. out projection
    gemm_bf16_kernel<<<dim3(HD/64, M/128), 256, 0, stream>>>(
        AOh, AOl, WoutTh, WoutTl, out, M, HD, CIN);
}

// Round 6
// 262.058 us; speedup vs baseline: 1.0320x; 1.0320x over previous
//
#include <hip/hip_runtime.h>
#include <cfloat>
#include <cstdint>

#define BATCH 2
#define NSEQ 2048
#define CIN 512
#define HEADS 8
#define DIM 64
#define HD 512
#define QKV3 1536

typedef short short8 __attribute__((ext_vector_type(8)));
typedef float f32x4 __attribute__((ext_vector_type(4)));
typedef unsigned short ushort_t;

__device__ __forceinline__ unsigned short f2bf(float f) {
    return (unsigned short)(__float_as_uint(f) >> 16);
}
__device__ __forceinline__ float bf2f(unsigned short h) {
    return __uint_as_float(((unsigned int)h) << 16);
}

// ---------- split + transpose weights: W[K][N] f32 -> WT[N][K] bf16 hi/lo ----
__global__ __launch_bounds__(256) void split_wT_kernel(
    const float* __restrict__ W, ushort_t* __restrict__ WTh,
    ushort_t* __restrict__ WTl, int K, int N)
{
    __shared__ float T[64][65];
    const int k0 = blockIdx.y * 64, n0 = blockIdx.x * 64;
    const int tid = threadIdx.x;
    #pragma unroll
    for (int i = 0; i < 4; ++i) {
        int c = tid + i * 256;
        int row = c >> 4, c4 = c & 15;
        *(float4*)&T[row][c4*4] = *(const float4*)(W + (size_t)(k0 + row) * N + n0 + c4*4);
    }
    __syncthreads();
    const int n = tid >> 2, kseg = tid & 3;
    short8 hh0, ll0, hh1, ll1;
    #pragma unroll
    for (int e = 0; e < 8; ++e) {
        float x0 = T[kseg*16 + e][n];
        unsigned short h0 = f2bf(x0);
        hh0[e] = (short)h0; ll0[e] = (short)f2bf(x0 - bf2f(h0));
        float x1 = T[kseg*16 + 8 + e][n];
        unsigned short h1 = f2bf(x1);
        hh1[e] = (short)h1; ll1[e] = (short)f2bf(x1 - bf2f(h1));
    }
    size_t o = (size_t)(n0 + n) * K + k0 + kseg * 16;
    *(short8*)(WTh + o)     = hh0;
    *(short8*)(WTh + o + 8) = hh1;
    *(short8*)(WTl + o)     = ll0;
    *(short8*)(WTl + o + 8) = ll1;
}

// ---------- split flat f32 array -> bf16 hi/lo --------------------------
__global__ __launch_bounds__(256) void split_f32_kernel(
    const float* __restrict__ X, ushort_t* __restrict__ Xh,
    ushort_t* __restrict__ Xl)
{
    int i = blockIdx.x * 256 + threadIdx.x;
    float4 a = ((const float4*)X)[i*2];
    float4 c = ((const float4*)X)[i*2 + 1];
    float v[8] = {a.x,a.y,a.z,a.w,c.x,c.y,c.z,c.w};
    short8 hh, ll;
    #pragma unroll
    for (int e = 0; e < 8; ++e) {
        unsigned short hi = f2bf(v[e]);
        hh[e] = (short)hi;
        ll[e] = (short)f2bf(v[e] - bf2f(hi));
    }
    *(short8*)(Xh + (size_t)i*8) = hh;
    *(short8*)(Xl + (size_t)i*8) = ll;
}

// ---------- split-bf16 MFMA GEMM: C = A(h/l)[M][K] @ BT(h/l)[N][K] ------
__global__ __launch_bounds__(256, 2) void gemm_bf16_kernel(
    const ushort_t* __restrict__ Ah, const ushort_t* __restrict__ Al,
    const ushort_t* __restrict__ BTh, const ushort_t* __restrict__ BTl,
    float* __restrict__ C, int M, int N, int K)
{
    __shared__ ushort_t Ash[128][72], Asl[128][72];
    __shared__ ushort_t Bsh[64][72],  Bsl[64][72];
    const int bm = blockIdx.y * 128, bn = blockIdx.x * 64;
    const int tid = threadIdx.x;
    const int wave = tid >> 6, lane = tid & 63;
    const int lg = lane >> 4, lm = lane & 15;
    const int wm = wave >> 1, wn = wave & 1;
    const int arow = tid >> 3, aseg = tid & 7;

    f32x4 acc[4][2];
    #pragma unroll
    for (int mf = 0; mf < 4; ++mf)
        #pragma unroll
        for (int nf = 0; nf < 2; ++nf) acc[mf][nf] = (f32x4){0.f,0.f,0.f,0.f};

    uint4 arh[4], arl[4], brh[2], brl[2];
    const int nkt = K >> 6;

    #define G_ISSUE(K0)                                                        \
        { _Pragma("unroll")                                                    \
          for (int i = 0; i < 4; ++i) {                                        \
            size_t ao = (size_t)(bm + arow + 32*i) * K + (K0) + aseg*8;        \
            arh[i] = *(const uint4*)(Ah + ao);                                 \
            arl[i] = *(const uint4*)(Al + ao);                                 \
          }                                                                    \
          _Pragma("unroll")                                                    \
          for (int i = 0; i < 2; ++i) {                                        \
            size_t bo = (size_t)(bn + arow + 32*i) * K + (K0) + aseg*8;        \
            brh[i] = *(const uint4*)(BTh + bo);                                \
            brl[i] = *(const uint4*)(BTl + bo);                                \
          } }

    G_ISSUE(0)
    for (int kt = 0; kt < nkt; ++kt) {
        __syncthreads();
        #pragma unroll
        for (int i = 0; i < 4; ++i) {
            *(uint4*)&Ash[arow + 32*i][aseg*8] = arh[i];
            *(uint4*)&Asl[arow + 32*i][aseg*8] = arl[i];
        }
        #pragma unroll
        for (int i = 0; i < 2; ++i) {
            *(uint4*)&Bsh[arow + 32*i][aseg*8] = brh[i];
            *(uint4*)&Bsl[arow + 32*i][aseg*8] = brl[i];
        }
        if (kt + 1 < nkt) G_ISSUE((kt + 1) * 64)
        __syncthreads();
        #pragma unroll
        for (int ks = 0; ks < 2; ++ks) {
            short8 afh[4], afl[4], bfh[2], bfl[2];
            #pragma unroll
            for (int mf = 0; mf < 4; ++mf) {
                afh[mf] = *(const short8*)&Ash[wm*64 + mf*16 + lm][ks*32 + lg*8];
                afl[mf] = *(const short8*)&Asl[wm*64 + mf*16 + lm][ks*32 + lg*8];
            }
            #pragma unroll
            for (int nf = 0; nf < 2; ++nf) {
                bfh[nf] = *(const short8*)&Bsh[wn*32 + nf*16 + lm][ks*32 + lg*8];
                bfl[nf] = *(const short8*)&Bsl[wn*32 + nf*16 + lm][ks*32 + lg*8];
            }
            #pragma unroll
            for (int mf = 0; mf < 4; ++mf)
                #pragma unroll
                for (int nf = 0; nf < 2; ++nf) {
                    acc[mf][nf] = __builtin_amdgcn_mfma_f32_16x16x32_bf16(afh[mf], bfh[nf], acc[mf][nf], 0, 0, 0);
                    acc[mf][nf] = __builtin_amdgcn_mfma_f32_16x16x32_bf16(afh[mf], bfl[nf], acc[mf][nf], 0, 0, 0);
                    acc[mf][nf] = __builtin_amdgcn_mfma_f32_16x16x32_bf16(afl[mf], bfh[nf], acc[mf][nf], 0, 0, 0);
                }
        }
    }
    #pragma unroll
    for (int mf = 0; mf < 4; ++mf)
        #pragma unroll
        for (int nf = 0; nf < 2; ++nf)
            #pragma unroll
            for (int r = 0; r < 4; ++r)
                C[(size_t)(bm + wm*64 + mf*16 + lg*4 + r) * N + bn + wn*32 + nf*16 + lm]
                    = acc[mf][nf][r];
    #undef G_ISSUE
}

// ------- fused qkv prep: l2norm+split Q,K  and  transposed/permuted V ----
__global__ __launch_bounds__(256) void qkv_prep_kernel(
    const float* __restrict__ qkv,
    ushort_t* __restrict__ Qh, ushort_t* __restrict__ Ql,
    ushort_t* __restrict__ Kh, ushort_t* __restrict__ Kl,
    ushort_t* __restrict__ Vth, ushort_t* __restrict__ Vtl)
{
    __shared__ float Vf[64][65];
    const int id = blockIdx.x;
    const int bh = id >> 5, nt = id & 31;
    const int b = bh >> 3, h = bh & 7;
    const int n0 = nt * 64;
    const int tid = threadIdx.x;
    {
        const int row = tid >> 2, dseg = tid & 3;
        const float* src = qkv + ((size_t)(b * NSEQ + n0 + row)) * QKV3
                         + h * 192 + dseg * 48;
        float f[48];
        #pragma unroll
        for (int i = 0; i < 12; ++i)
            *(float4*)&f[i*4] = *(const float4*)(src + i*4);
        float nq = 0.f, nk = 0.f;
        #pragma unroll
        for (int e = 0; e < 16; ++e) {
            nq = fmaf(f[3*e], f[3*e], nq);
            nk = fmaf(f[3*e+1], f[3*e+1], nk);
        }
        nq += __shfl_xor(nq, 1); nq += __shfl_xor(nq, 2);
        nk += __shfl_xor(nk, 1); nk += __shfl_xor(nk, 2);
        float rq = 1.f / fmaxf(sqrtf(nq), 1e-12f);
        float rk = 1.f / fmaxf(sqrtf(nk), 1e-12f);
        short8 qh8[2], ql8[2], kh8[2], kl8[2];
        #pragma unroll
        for (int e = 0; e < 16; ++e) {
            float q = f[3*e] * rq, k = f[3*e+1] * rk;
            unsigned short qhi = f2bf(q), khi = f2bf(k);
            qh8[e>>3][e&7] = (short)qhi;
            ql8[e>>3][e&7] = (short)f2bf(q - bf2f(qhi));
            kh8[e>>3][e&7] = (short)khi;
            kl8[e>>3][e&7] = (short)f2bf(k - bf2f(khi));
            Vf[dseg*16 + e][row] = f[3*e+2];
        }
        size_t o = ((size_t)bh * NSEQ + n0 + row) * DIM + dseg * 16;
        *(short8*)(Qh + o) = qh8[0]; *(short8*)(Qh + o + 8) = qh8[1];
        *(short8*)(Ql + o) = ql8[0]; *(short8*)(Ql + o + 8) = ql8[1];
        *(short8*)(Kh + o) = kh8[0]; *(short8*)(Kh + o + 8) = kh8[1];
        *(short8*)(Kl + o) = kl8[0]; *(short8*)(Kl + o + 8) = kl8[1];
    }
    __syncthreads();
    {   // Vt[bh][d][n] with the PV fragment j-permutation (within 32-blocks)
        const int d = tid >> 2, seg = tid & 3;
        ushort_t th[16], tl[16];
        #pragma unroll
        for (int t = 0; t < 16; ++t) {
            int p = seg * 16 + t;
            int s = (p & 35) | ((p & 4) << 2) | ((p >> 1) & 12);
            float v = Vf[d][s];
            unsigned short hi = f2bf(v);
            th[t] = hi;
            tl[t] = f2bf(v - bf2f(hi));
        }
        size_t o = ((size_t)bh * DIM + d) * NSEQ + n0 + seg * 16;
        *(uint4*)(Vth + o)     = *(uint4*)&th[0];
        *(uint4*)(Vth + o + 8) = *(uint4*)&th[8];
        *(uint4*)(Vtl + o)     = *(uint4*)&tl[0];
        *(uint4*)(Vtl + o + 8) = *(uint4*)&tl[8];
    }
}

// ---------------- MFMA flash attention v6 --------------------------------
// Q-tile 128 (4 waves x 32 rows), KVBLK=32 dbuf, j-split 3, grid 768
__global__ __launch_bounds__(256, 3) void attn_mfma_kernel(
    const ushort_t* __restrict__ Qh, const ushort_t* __restrict__ Ql,
    const ushort_t* __restrict__ Kh, const ushort_t* __restrict__ Kl,
    const ushort_t* __restrict__ Vth, const ushort_t* __restrict__ Vtl,
    const float* __restrict__ bias, const float* __restrict__ temp_p,
    const uint8_t* __restrict__ mask,
    float* __restrict__ Opart, float* __restrict__ Ml)
{
    __shared__ ushort_t KsH[2][32][72], KsL[2][32][72];   // [buf][j][d]
    __shared__ ushort_t VsH[2][64][36], VsL[2][64][36];   // [buf][d][j-perm]

    const int id = blockIdx.x;
    const int h = id & 7;                  // XCD-grouped
    const int rest = id >> 3;              // 0..95
    const int b = rest / 48;
    const int r2 = rest % 48;
    const int js = r2 / 16;                // 0..2
    const int qt = r2 & 15;
    const int bh = b * 8 + h;
    const int i0 = qt * 128;
    const int tid = threadIdx.x;
    const int wave = tid >> 6, lane = tid & 63;
    const int lg = lane >> 4, lm = lane & 15;
    const int qbase = i0 + wave * 32;
    const float temp = *temp_p;
    const int krow = tid >> 3, kseg = tid & 7;   // K staging: 32 x 8
    const int vrow = tid >> 2, vseg = tid & 3;   // V staging: 64 x 4

    short8 qfh[2][2], qfl[2][2];
    #pragma unroll
    for (int m = 0; m < 2; ++m) {
        size_t qo = ((size_t)(bh * NSEQ + qbase + 16*m + lm)) * DIM + lg * 8;
        qfh[m][0] = *(const short8*)(Qh + qo);
        qfh[m][1] = *(const short8*)(Qh + qo + 32);
        qfl[m][0] = *(const short8*)(Ql + qo);
        qfl[m][1] = *(const short8*)(Ql + qo + 32);
    }
    bool rowm[2];
    rowm[0] = mask[(size_t)b * NSEQ + qbase + lm] != 0;
    rowm[1] = mask[(size_t)b * NSEQ + qbase + 16 + lm] != 0;

    float m_r[2] = {-FLT_MAX, -FLT_MAX};
    float l_r[2] = {0.f, 0.f};
    f32x4 oa[2][4];
    #pragma unroll
    for (int m = 0; m < 2; ++m)
        #pragma unroll
        for (int dt = 0; dt < 4; ++dt) oa[m][dt] = (f32x4){0.f,0.f,0.f,0.f};

    // uneven 3-way split of 64 tiles: 22 / 21 / 21
    const int NT = 21 + (js == 0);
    const int tstart = js * 21 + (js > 0);
    const int jbase = tstart * 32;
    uint4 skh, skl, svh, svl;

    #define A_ISSUE(J0) {                                                      \
        size_t gk = ((size_t)(bh * NSEQ) + (J0) + krow) * DIM + kseg*8;        \
        size_t gv = ((size_t)(bh * DIM) + vrow) * NSEQ + (J0) + vseg*8;        \
        skh = *(const uint4*)(Kh  + gk);                                       \
        skl = *(const uint4*)(Kl  + gk);                                       \
        svh = *(const uint4*)(Vth + gv);                                       \
        svl = *(const uint4*)(Vtl + gv); }
    #define STAGE(BUF) {                                                       \
        *(uint4*)&KsH[BUF][krow][kseg*8] = skh;                                \
        *(uint4*)&KsL[BUF][krow][kseg*8] = skl;                                \
        *(uint4*)&VsH[BUF][vrow][vseg*8] = svh;                                \
        *(uint4*)&VsL[BUF][vrow][vseg*8] = svl; }

    A_ISSUE(jbase)
    STAGE(0)
    A_ISSUE(jbase + 32)
    float4 bb[2][2];
    #pragma unroll
    for (int m = 0; m < 2; ++m)
        #pragma unroll
        for (int jt = 0; jt < 2; ++jt)
            bb[m][jt] = *(const float4*)(bias
                + ((size_t)h * NSEQ + qbase + 16*m + lm) * NSEQ
                + jbase + jt*16 + lg*4);
    uint8_t mk = mask[(size_t)b * NSEQ + jbase + (lane & 31)];
    __syncthreads();

    #pragma unroll 2
    for (int t = 0; t < NT; ++t) {
        const int cur = t & 1;
        const int j0 = jbase + t * 32;

        // ---- prefetch next tile's bias/mask; stage t+1; issue t+2 ----
        float4 bbn[2][2];
        uint8_t mkn = 0;
        if (t + 1 < NT) {
            #pragma unroll
            for (int m = 0; m < 2; ++m)
                #pragma unroll
                for (int jt = 0; jt < 2; ++jt)
                    bbn[m][jt] = *(const float4*)(bias
                        + ((size_t)h * NSEQ + qbase + 16*m + lm) * NSEQ
                        + j0 + 32 + jt*16 + lg*4);
            mkn = mask[(size_t)b * NSEQ + j0 + 32 + (lane & 31)];
            STAGE(cur ^ 1)
            if (t + 2 < NT) A_ISSUE(j0 + 64)
        }
        unsigned long long bal = __ballot(mk != 0);   // low 32 bits = tile cols

        // ---- S^T = K.Q (swapped), split MFMA ----
        f32x4 sac[2][2];
        #pragma unroll
        for (int m = 0; m < 2; ++m)
            #pragma unroll
            for (int jt = 0; jt < 2; ++jt) sac[m][jt] = (f32x4){0.f,0.f,0.f,0.f};
        __builtin_amdgcn_s_setprio(1);
        #pragma unroll
        for (int jt = 0; jt < 2; ++jt)
            #pragma unroll
            for (int ks = 0; ks < 2; ++ks) {
                short8 kbh = *(const short8*)(&KsH[cur][jt*16 + lm][ks*32 + lg*8]);
                short8 kbl = *(const short8*)(&KsL[cur][jt*16 + lm][ks*32 + lg*8]);
                #pragma unroll
                for (int m = 0; m < 2; ++m) {
                    sac[m][jt] = __builtin_amdgcn_mfma_f32_16x16x32_bf16(kbh, qfh[m][ks], sac[m][jt], 0, 0, 0);
                    sac[m][jt] = __builtin_amdgcn_mfma_f32_16x16x32_bf16(kbh, qfl[m][ks], sac[m][jt], 0, 0, 0);
                    sac[m][jt] = __builtin_amdgcn_mfma_f32_16x16x32_bf16(kbl, qfh[m][ks], sac[m][jt], 0, 0, 0);
                }
            }
        __builtin_amdgcn_s_setprio(0);

        // ---- in-register online softmax with defer-max ----
        short8 pah[2], pal[2];
        #pragma unroll
        for (int m = 0; m < 2; ++m) {
            float sv[2][4];
            #pragma unroll
            for (int jt = 0; jt < 2; ++jt) {
                unsigned int nib = (unsigned int)(bal >> (jt*16 + lg*4)) & 0xFu;
                #pragma unroll
                for (int r = 0; r < 4; ++r) {
                    bool dead = rowm[m] || ((nib >> r) & 1u);
                    float bv = (r == 0) ? bb[m][jt].x : (r == 1) ? bb[m][jt].y
                             : (r == 2) ? bb[m][jt].z : bb[m][jt].w;
                    sv[jt][r] = dead ? -FLT_MAX : fmaf(sac[m][jt][r], temp, bv);
                }
            }
            float pmax = fmaxf(fmaxf(fmaxf(sv[0][0], sv[0][1]), fmaxf(sv[0][2], sv[0][3])),
                               fmaxf(fmaxf(sv[1][0], sv[1][1]), fmaxf(sv[1][2], sv[1][3])));
            pmax = fmaxf(pmax, __shfl_xor(pmax, 16));
            pmax = fmaxf(pmax, __shfl_xor(pmax, 32));
            if (!__all(pmax <= m_r[m] + 8.f)) {      // rare rescale
                float mn = fmaxf(m_r[m], pmax);
                float sc = __expf(m_r[m] - mn);
                m_r[m] = mn;
                l_r[m] *= sc;
                #pragma unroll
                for (int r = 0; r < 4; ++r) {
                    float sq = __shfl(sc, lg*4 + r);
                    #pragma unroll
                    for (int dt = 0; dt < 4; ++dt) oa[m][dt][r] *= sq;
                }
            }
            float rs = 0.f;
            #pragma unroll
            for (int jt = 0; jt < 2; ++jt)
                #pragma unroll
                for (int r = 0; r < 4; ++r) {
                    float pf = __expf(sv[jt][r] - m_r[m]);
                    rs += pf;
                    unsigned short hi = f2bf(pf);
                    pah[m][jt*4 + r] = (short)hi;
                    pal[m][jt*4 + r] = (short)f2bf(pf - bf2f(hi));
                }
            rs += __shfl_xor(rs, 16);
            rs += __shfl_xor(rs, 32);
            l_r[m] += rs;
        }

        // ---- O += P.V ----
        __builtin_amdgcn_s_setprio(1);
        #pragma unroll
        for (int dt = 0; dt < 4; ++dt) {
            short8 vbh = *(const short8*)(&VsH[cur][dt*16 + lm][lg*8]);
            short8 vbl = *(const short8*)(&VsL[cur][dt*16 + lm][lg*8]);
            #pragma unroll
            for (int m = 0; m < 2; ++m) {
                oa[m][dt] = __builtin_amdgcn_mfma_f32_16x16x32_bf16(pah[m], vbh, oa[m][dt], 0, 0, 0);
                oa[m][dt] = __builtin_amdgcn_mfma_f32_16x16x32_bf16(pah[m], vbl, oa[m][dt], 0, 0, 0);
                oa[m][dt] = __builtin_amdgcn_mfma_f32_16x16x32_bf16(pal[m], vbh, oa[m][dt], 0, 0, 0);
            }
        }
        __builtin_amdgcn_s_setprio(0);
        __syncthreads();
        #pragma unroll
        for (int m = 0; m < 2; ++m)
            #pragma unroll
            for (int jt = 0; jt < 2; ++jt) bb[m][jt] = bbn[m][jt];
        mk = mkn;
    }
    #undef A_ISSUE
    #undef STAGE

    // ---- epilogue: f32 partials + (m,l) ----
    #pragma unroll
    for (int m = 0; m < 2; ++m)
        #pragma unroll
        for (int dt = 0; dt < 4; ++dt)
            #pragma unroll
            for (int r = 0; r < 4; ++r)
                Opart[((size_t)(js*16 + bh) * NSEQ + qbase + 16*m + lg*4 + r) * 64
                      + dt*16 + lm] = oa[m][dt][r];
    if (lane < 16) {
        #pragma unroll
        for (int m = 0; m < 2; ++m) {
            size_t mi = ((size_t)(js*16 + bh) * NSEQ + qbase + 16*m + lm) * 2;
            Ml[mi]     = m_r[m];
            Ml[mi + 1] = l_r[m];
        }
    }
}

// ------- merge 3 j-split partials -> AO bf16 hi/lo [M][HD] --------------
__global__ __launch_bounds__(256) void merge_kernel(
    const float* __restrict__ Opart, const float* __restrict__ Ml,
    ushort_t* __restrict__ AOh, ushort_t* __restrict__ AOl)
{
    int row = blockIdx.x * 4 + (threadIdx.x >> 6);
    int d = threadIdx.x & 63;
    int bh = row >> 11, n = row & (NSEQ - 1);
    int bq = bh >> 3, hq = bh & 7;
    float mv[3], lv[3];
    float mm = -FLT_MAX;
    #pragma unroll
    for (int p = 0; p < 3; ++p) {
        size_t mi = ((size_t)(p*16 + bh) * NSEQ + n) * 2;
        mv[p] = Ml[mi]; lv[p] = Ml[mi + 1];
        mm = fmaxf(mm, mv[p]);
    }
    float l = 0.f, o = 0.f;
    #pragma unroll
    for (int p = 0; p < 3; ++p) {
        float w = __expf(mv[p] - mm);
        l += lv[p] * w;
        o += Opart[((size_t)(p*16 + bh) * NSEQ + n) * 64 + d] * w;
    }
    o /= l;
    size_t oi = ((size_t)(bq * NSEQ + n)) * HD + hq * DIM + d;
    unsigned short hi = f2bf(o);
    AOh[oi] = hi;
    AOl[oi] = f2bf(o - bf2f(hi));
}

extern "C" void kernel_launch(void* const* d_in, const int* in_sizes, int n_in,
                              void* d_out, int out_size, void* d_ws, size_t ws_size,
                              hipStream_t stream)
{
    const float*   x        = (const float*)d_in[0];
    const float*   w_qkv    = (const float*)d_in[1];
    const float*   w_out    = (const float*)d_in[2];
    const float*   pos_bias = (const float*)d_in[3];
    const float*   temp     = (const float*)d_in[4];
    const uint8_t* mask     = (const uint8_t*)d_in[5];
    float* out = (float*)d_out;

    const int M = BATCH * NSEQ;                        // 4096
    const size_t NE = (size_t)BATCH * HEADS * NSEQ * DIM;
    char* ws = (char*)d_ws;

    // region 0 (25.2 MB): qkv_lin f32; exactly reused for 3-split f32 Opart
    float* qkv_lin = (float*)ws;
    float* OpartP  = (float*)ws;    // 3*16*2048*64*4 B == M*QKV3*4 B exactly
    size_t off = (size_t)M * QKV3 * 4;
    // region 1 (4.2 MB + 0.79 MB): transposed/split weights + Ml
    ushort_t* WqkvTh = (ushort_t*)(ws + off); off += (size_t)QKV3 * CIN * 2;
    ushort_t* WqkvTl = (ushort_t*)(ws + off); off += (size_t)QKV3 * CIN * 2;
    ushort_t* WoutTh = (ushort_t*)(ws + off); off += (size_t)HD * CIN * 2;
    ushort_t* WoutTl = (ushort_t*)(ws + off); off += (size_t)HD * CIN * 2;
    float*    MlP    = (float*)(ws + off);    off += (size_t)3 * 16 * NSEQ * 2 * 4;
    // region 2 (25.2 MB): phase A: xh/xl; phase B: Q/K/Vt; phase C: AOh/AOl
    char* reg2 = ws + off;
    ushort_t* Qh  = (ushort_t*)reg2;
    ushort_t* Ql  = Qh + NE;
    ushort_t* Kh  = Ql + NE;
    ushort_t* Kl  = Kh + NE;
    ushort_t* Vth = Kl + NE;
    ushort_t* Vtl = Vth + NE;
    ushort_t* xh  = Qh, *xl = Ql;
    ushort_t* AOh = Qh, *AOl = Ql;

    // 1. weight split+transpose
    split_wT_kernel<<<dim3(QKV3/64, CIN/64), 256, 0, stream>>>(w_qkv, WqkvTh, WqkvTl, CIN, QKV3);
    split_wT_kernel<<<dim3(HD/64,  CIN/64), 256, 0, stream>>>(w_out, WoutTh, WoutTl, CIN, HD);
    // 2. split x -> bf16 hi/lo
    split_f32_kernel<<<dim3((M * CIN) / (256 * 8)), 256, 0, stream>>>(x, xh, xl);
    // 3. qkv projection
    gemm_bf16_kernel<<<dim3(QKV3/64, M/128), 256, 0, stream>>>(
        xh, xl, WqkvTh, WqkvTl, qkv_lin, M, QKV3, CIN);
    // 4. fused l2norm/split + V transpose (overwrites xh/xl)
    qkv_prep_kernel<<<dim3(BATCH * HEADS * (NSEQ/64)), 256, 0, stream>>>(
        qkv_lin, Qh, Ql, Kh, Kl, Vth, Vtl);
    // 5. attention (j-split 3; Opart overwrites qkv_lin)
    attn_mfma_kernel<<<dim3(768), 256, 0, stream>>>(
        Qh, Ql, Kh, Kl, Vth, Vtl, pos_bias, temp, mask, OpartP, MlP);
    // 6. merge partials -> AO bf16 hi/lo (overwrites Qh/Ql)
    merge_kernel<<<dim3(M * HEADS / 4), 256, 0, stream>>>(OpartP, MlP, AOh, AOl);
    // 7. out projection
    gemm_bf16_kernel<<<dim3(HD/64, M/128), 256, 0, stream>>>(
        AOh, AOl, WoutTh, WoutTl, out, M, HD, CIN);
}

// Round 7
// 206.314 us; speedup vs baseline: 1.3109x; 1.2702x over previous
//
#include <hip/hip_runtime.h>
#include <cfloat>
#include <cstdint>

#define BATCH 2
#define NSEQ 2048
#define CIN 512
#define HEADS 8
#define DIM 64
#define HD 512
#define QKV3 1536

typedef short short8 __attribute__((ext_vector_type(8)));
typedef float f32x4 __attribute__((ext_vector_type(4)));
typedef unsigned short ushort_t;

__device__ __forceinline__ unsigned short f2bf(float f) {
    return (unsigned short)(__float_as_uint(f) >> 16);
}
__device__ __forceinline__ float bf2f(unsigned short h) {
    return __uint_as_float(((unsigned int)h) << 16);
}

// ---------- split + transpose weights: W[K][N] f32 -> WT[N][K] bf16 hi/lo ----
__global__ __launch_bounds__(256) void split_wT_kernel(
    const float* __restrict__ W, ushort_t* __restrict__ WTh,
    ushort_t* __restrict__ WTl, int K, int N)
{
    __shared__ float T[64][65];
    const int k0 = blockIdx.y * 64, n0 = blockIdx.x * 64;
    const int tid = threadIdx.x;
    #pragma unroll
    for (int i = 0; i < 4; ++i) {
        int c = tid + i * 256;
        int row = c >> 4, c4 = c & 15;
        *(float4*)&T[row][c4*4] = *(const float4*)(W + (size_t)(k0 + row) * N + n0 + c4*4);
    }
    __syncthreads();
    const int n = tid >> 2, kseg = tid & 3;
    short8 hh0, ll0, hh1, ll1;
    #pragma unroll
    for (int e = 0; e < 8; ++e) {
        float x0 = T[kseg*16 + e][n];
        unsigned short h0 = f2bf(x0);
        hh0[e] = (short)h0; ll0[e] = (short)f2bf(x0 - bf2f(h0));
        float x1 = T[kseg*16 + 8 + e][n];
        unsigned short h1 = f2bf(x1);
        hh1[e] = (short)h1; ll1[e] = (short)f2bf(x1 - bf2f(h1));
    }
    size_t o = (size_t)(n0 + n) * K + k0 + kseg * 16;
    *(short8*)(WTh + o)     = hh0;
    *(short8*)(WTh + o + 8) = hh1;
    *(short8*)(WTl + o)     = ll0;
    *(short8*)(WTl + o + 8) = ll1;
}

// ---------- split-bf16 MFMA GEMM: C[M][N] = A[M][K](f32) @ BT[N][K](bf16 h/l) --
// BM=128 BN=64 BK=64, 256 thr (4 waves), wave-tile 64x32   [R3-proven]
__global__ __launch_bounds__(256, 2) void gemm_split_kernel(
    const float* __restrict__ A, const ushort_t* __restrict__ BTh,
    const ushort_t* __restrict__ BTl, float* __restrict__ C,
    int M, int N, int K)
{
    __shared__ ushort_t Ash[128][72], Asl[128][72];
    __shared__ ushort_t Bsh[64][72],  Bsl[64][72];
    const int bm = blockIdx.y * 128, bn = blockIdx.x * 64;
    const int tid = threadIdx.x;
    const int wave = tid >> 6, lane = tid & 63;
    const int lg = lane >> 4, lm = lane & 15;
    const int wm = wave >> 1, wn = wave & 1;
    const int arow = tid >> 3, aseg = tid & 7;   // +32*i rows

    f32x4 acc[4][2];
    #pragma unroll
    for (int mf = 0; mf < 4; ++mf)
        #pragma unroll
        for (int nf = 0; nf < 2; ++nf) acc[mf][nf] = (f32x4){0.f,0.f,0.f,0.f};

    float4 ar[8];
    uint4 brh[2], brl[2];
    const int nkt = K >> 6;

    #define G_ISSUE(K0)                                                          \
        { _Pragma("unroll")                                                      \
          for (int i = 0; i < 4; ++i) {                                          \
            const float* ap = A + (size_t)(bm + arow + 32*i) * K + (K0) + aseg*8;\
            ar[2*i]   = *(const float4*)ap;                                      \
            ar[2*i+1] = *(const float4*)(ap + 4);                                \
          }                                                                      \
          _Pragma("unroll")                                                      \
          for (int i = 0; i < 2; ++i) {                                          \
            size_t bo = (size_t)(bn + arow + 32*i) * K + (K0) + aseg*8;          \
            brh[i] = *(const uint4*)(BTh + bo);                                  \
            brl[i] = *(const uint4*)(BTl + bo);                                  \
          } }

    G_ISSUE(0)
    for (int kt = 0; kt < nkt; ++kt) {
        __syncthreads();
        #pragma unroll
        for (int i = 0; i < 4; ++i) {
            float av[8];
            *(float4*)&av[0] = ar[2*i];
            *(float4*)&av[4] = ar[2*i+1];
            short8 hh, ll;
            #pragma unroll
            for (int e = 0; e < 8; ++e) {
                unsigned short hi = f2bf(av[e]);
                hh[e] = (short)hi;
                ll[e] = (short)f2bf(av[e] - bf2f(hi));
            }
            *(short8*)&Ash[arow + 32*i][aseg*8] = hh;
            *(short8*)&Asl[arow + 32*i][aseg*8] = ll;
        }
        #pragma unroll
        for (int i = 0; i < 2; ++i) {
            *(uint4*)&Bsh[arow + 32*i][aseg*8] = brh[i];
            *(uint4*)&Bsl[arow + 32*i][aseg*8] = brl[i];
        }
        if (kt + 1 < nkt) G_ISSUE((kt + 1) * 64)
        __syncthreads();
        #pragma unroll
        for (int ks = 0; ks < 2; ++ks) {
            short8 afh[4], afl[4], bfh[2], bfl[2];
            #pragma unroll
            for (int mf = 0; mf < 4; ++mf) {
                afh[mf] = *(const short8*)&Ash[wm*64 + mf*16 + lm][ks*32 + lg*8];
                afl[mf] = *(const short8*)&Asl[wm*64 + mf*16 + lm][ks*32 + lg*8];
            }
            #pragma unroll
            for (int nf = 0; nf < 2; ++nf) {
                bfh[nf] = *(const short8*)&Bsh[wn*32 + nf*16 + lm][ks*32 + lg*8];
                bfl[nf] = *(const short8*)&Bsl[wn*32 + nf*16 + lm][ks*32 + lg*8];
            }
            #pragma unroll
            for (int mf = 0; mf < 4; ++mf)
                #pragma unroll
                for (int nf = 0; nf < 2; ++nf) {
                    acc[mf][nf] = __builtin_amdgcn_mfma_f32_16x16x32_bf16(afh[mf], bfh[nf], acc[mf][nf], 0, 0, 0);
                    acc[mf][nf] = __builtin_amdgcn_mfma_f32_16x16x32_bf16(afh[mf], bfl[nf], acc[mf][nf], 0, 0, 0);
                    acc[mf][nf] = __builtin_amdgcn_mfma_f32_16x16x32_bf16(afl[mf], bfh[nf], acc[mf][nf], 0, 0, 0);
                }
        }
    }
    #pragma unroll
    for (int mf = 0; mf < 4; ++mf)
        #pragma unroll
        for (int nf = 0; nf < 2; ++nf)
            #pragma unroll
            for (int r = 0; r < 4; ++r)
                C[(size_t)(bm + wm*64 + mf*16 + lg*4 + r) * N + bn + wn*32 + nf*16 + lm]
                    = acc[mf][nf][r];
    #undef G_ISSUE
}

// ------- fused qkv prep: l2norm+split Q,K  and  transposed/permuted V ----
__global__ __launch_bounds__(256) void qkv_prep_kernel(
    const float* __restrict__ qkv,
    ushort_t* __restrict__ Qh, ushort_t* __restrict__ Ql,
    ushort_t* __restrict__ Kh, ushort_t* __restrict__ Kl,
    ushort_t* __restrict__ Vth, ushort_t* __restrict__ Vtl)
{
    __shared__ float Vf[64][65];
    const int id = blockIdx.x;
    const int bh = id >> 5, nt = id & 31;
    const int b = bh >> 3, h = bh & 7;
    const int n0 = nt * 64;
    const int tid = threadIdx.x;
    {
        const int row = tid >> 2, dseg = tid & 3;
        const float* src = qkv + ((size_t)(b * NSEQ + n0 + row)) * QKV3
                         + h * 192 + dseg * 48;
        float f[48];
        #pragma unroll
        for (int i = 0; i < 12; ++i)
            *(float4*)&f[i*4] = *(const float4*)(src + i*4);
        float nq = 0.f, nk = 0.f;
        #pragma unroll
        for (int e = 0; e < 16; ++e) {
            nq = fmaf(f[3*e], f[3*e], nq);
            nk = fmaf(f[3*e+1], f[3*e+1], nk);
        }
        nq += __shfl_xor(nq, 1); nq += __shfl_xor(nq, 2);
        nk += __shfl_xor(nk, 1); nk += __shfl_xor(nk, 2);
        float rq = 1.f / fmaxf(sqrtf(nq), 1e-12f);
        float rk = 1.f / fmaxf(sqrtf(nk), 1e-12f);
        short8 qh8[2], ql8[2], kh8[2], kl8[2];
        #pragma unroll
        for (int e = 0; e < 16; ++e) {
            float q = f[3*e] * rq, k = f[3*e+1] * rk;
            unsigned short qhi = f2bf(q), khi = f2bf(k);
            qh8[e>>3][e&7] = (short)qhi;
            ql8[e>>3][e&7] = (short)f2bf(q - bf2f(qhi));
            kh8[e>>3][e&7] = (short)khi;
            kl8[e>>3][e&7] = (short)f2bf(k - bf2f(khi));
            Vf[dseg*16 + e][row] = f[3*e+2];
        }
        size_t o = ((size_t)bh * NSEQ + n0 + row) * DIM + dseg * 16;
        *(short8*)(Qh + o) = qh8[0]; *(short8*)(Qh + o + 8) = qh8[1];
        *(short8*)(Ql + o) = ql8[0]; *(short8*)(Ql + o + 8) = ql8[1];
        *(short8*)(Kh + o) = kh8[0]; *(short8*)(Kh + o + 8) = kh8[1];
        *(short8*)(Kl + o) = kl8[0]; *(short8*)(Kl + o + 8) = kl8[1];
    }
    __syncthreads();
    {   // Vt[bh][d][n] with the PV fragment j-permutation (within 32-blocks)
        const int d = tid >> 2, seg = tid & 3;
        ushort_t th[16], tl[16];
        #pragma unroll
        for (int t = 0; t < 16; ++t) {
            int p = seg * 16 + t;
            int s = (p & 35) | ((p & 4) << 2) | ((p >> 1) & 12);
            float v = Vf[d][s];
            unsigned short hi = f2bf(v);
            th[t] = hi;
            tl[t] = f2bf(v - bf2f(hi));
        }
        size_t o = ((size_t)bh * DIM + d) * NSEQ + n0 + seg * 16;
        *(uint4*)(Vth + o)     = *(uint4*)&th[0];
        *(uint4*)(Vth + o + 8) = *(uint4*)&th[8];
        *(uint4*)(Vtl + o)     = *(uint4*)&tl[0];
        *(uint4*)(Vtl + o + 8) = *(uint4*)&tl[8];
    }
}

// ---------------- MFMA flash attention v6 (unchanged from R6) ------------
// Q-tile 128 (4 waves x 32 rows), KVBLK=32 dbuf, j-split 3, grid 768
__global__ __launch_bounds__(256, 3) void attn_mfma_kernel(
    const ushort_t* __restrict__ Qh, const ushort_t* __restrict__ Ql,
    const ushort_t* __restrict__ Kh, const ushort_t* __restrict__ Kl,
    const ushort_t* __restrict__ Vth, const ushort_t* __restrict__ Vtl,
    const float* __restrict__ bias, const float* __restrict__ temp_p,
    const uint8_t* __restrict__ mask,
    float* __restrict__ Opart, float* __restrict__ Ml)
{
    __shared__ ushort_t KsH[2][32][72], KsL[2][32][72];   // [buf][j][d]
    __shared__ ushort_t VsH[2][64][36], VsL[2][64][36];   // [buf][d][j-perm]

    const int id = blockIdx.x;
    const int h = id & 7;                  // XCD-grouped
    const int rest = id >> 3;              // 0..95
    const int b = rest / 48;
    const int r2 = rest % 48;
    const int js = r2 / 16;                // 0..2
    const int qt = r2 & 15;
    const int bh = b * 8 + h;
    const int i0 = qt * 128;
    const int tid = threadIdx.x;
    const int wave = tid >> 6, lane = tid & 63;
    const int lg = lane >> 4, lm = lane & 15;
    const int qbase = i0 + wave * 32;
    const float temp = *temp_p;
    const int krow = tid >> 3, kseg = tid & 7;   // K staging: 32 x 8
    const int vrow = tid >> 2, vseg = tid & 3;   // V staging: 64 x 4

    short8 qfh[2][2], qfl[2][2];
    #pragma unroll
    for (int m = 0; m < 2; ++m) {
        size_t qo = ((size_t)(bh * NSEQ + qbase + 16*m + lm)) * DIM + lg * 8;
        qfh[m][0] = *(const short8*)(Qh + qo);
        qfh[m][1] = *(const short8*)(Qh + qo + 32);
        qfl[m][0] = *(const short8*)(Ql + qo);
        qfl[m][1] = *(const short8*)(Ql + qo + 32);
    }
    bool rowm[2];
    rowm[0] = mask[(size_t)b * NSEQ + qbase + lm] != 0;
    rowm[1] = mask[(size_t)b * NSEQ + qbase + 16 + lm] != 0;

    float m_r[2] = {-FLT_MAX, -FLT_MAX};
    float l_r[2] = {0.f, 0.f};
    f32x4 oa[2][4];
    #pragma unroll
    for (int m = 0; m < 2; ++m)
        #pragma unroll
        for (int dt = 0; dt < 4; ++dt) oa[m][dt] = (f32x4){0.f,0.f,0.f,0.f};

    // uneven 3-way split of 64 tiles: 22 / 21 / 21
    const int NT = 21 + (js == 0);
    const int tstart = js * 21 + (js > 0);
    const int jbase = tstart * 32;
    uint4 skh, skl, svh, svl;

    #define A_ISSUE(J0) {                                                      \
        size_t gk = ((size_t)(bh * NSEQ) + (J0) + krow) * DIM + kseg*8;        \
        size_t gv = ((size_t)(bh * DIM) + vrow) * NSEQ + (J0) + vseg*8;        \
        skh = *(const uint4*)(Kh  + gk);                                       \
        skl = *(const uint4*)(Kl  + gk);                                       \
        svh = *(const uint4*)(Vth + gv);                                       \
        svl = *(const uint4*)(Vtl + gv); }
    #define STAGE(BUF) {                                                       \
        *(uint4*)&KsH[BUF][krow][kseg*8] = skh;                                \
        *(uint4*)&KsL[BUF][krow][kseg*8] = skl;                                \
        *(uint4*)&VsH[BUF][vrow][vseg*8] = svh;                                \
        *(uint4*)&VsL[BUF][vrow][vseg*8] = svl; }

    A_ISSUE(jbase)
    STAGE(0)
    A_ISSUE(jbase + 32)
    float4 bb[2][2];
    #pragma unroll
    for (int m = 0; m < 2; ++m)
        #pragma unroll
        for (int jt = 0; jt < 2; ++jt)
            bb[m][jt] = *(const float4*)(bias
                + ((size_t)h * NSEQ + qbase + 16*m + lm) * NSEQ
                + jbase + jt*16 + lg*4);
    uint8_t mk = mask[(size_t)b * NSEQ + jbase + (lane & 31)];
    __syncthreads();

    #pragma unroll 2
    for (int t = 0; t < NT; ++t) {
        const int cur = t & 1;
        const int j0 = jbase + t * 32;

        // ---- prefetch next tile's bias/mask; stage t+1; issue t+2 ----
        float4 bbn[2][2];
        uint8_t mkn = 0;
        if (t + 1 < NT) {
            #pragma unroll
            for (int m = 0; m < 2; ++m)
                #pragma unroll
                for (int jt = 0; jt < 2; ++jt)
                    bbn[m][jt] = *(const float4*)(bias
                        + ((size_t)h * NSEQ + qbase + 16*m + lm) * NSEQ
                        + j0 + 32 + jt*16 + lg*4);
            mkn = mask[(size_t)b * NSEQ + j0 + 32 + (lane & 31)];
            STAGE(cur ^ 1)
            if (t + 2 < NT) A_ISSUE(j0 + 64)
        }
        unsigned long long bal = __ballot(mk != 0);   // low 32 bits = tile cols

        // ---- S^T = K.Q (swapped), split MFMA ----
        f32x4 sac[2][2];
        #pragma unroll
        for (int m = 0; m < 2; ++m)
            #pragma unroll
            for (int jt = 0; jt < 2; ++jt) sac[m][jt] = (f32x4){0.f,0.f,0.f,0.f};
        __builtin_amdgcn_s_setprio(1);
        #pragma unroll
        for (int jt = 0; jt < 2; ++jt)
            #pragma unroll
            for (int ks = 0; ks < 2; ++ks) {
                short8 kbh = *(const short8*)(&KsH[cur][jt*16 + lm][ks*32 + lg*8]);
                short8 kbl = *(const short8*)(&KsL[cur][jt*16 + lm][ks*32 + lg*8]);
                #pragma unroll
                for (int m = 0; m < 2; ++m) {
                    sac[m][jt] = __builtin_amdgcn_mfma_f32_16x16x32_bf16(kbh, qfh[m][ks], sac[m][jt], 0, 0, 0);
                    sac[m][jt] = __builtin_amdgcn_mfma_f32_16x16x32_bf16(kbh, qfl[m][ks], sac[m][jt], 0, 0, 0);
                    sac[m][jt] = __builtin_amdgcn_mfma_f32_16x16x32_bf16(kbl, qfh[m][ks], sac[m][jt], 0, 0, 0);
                }
            }
        __builtin_amdgcn_s_setprio(0);

        // ---- in-register online softmax with defer-max ----
        short8 pah[2], pal[2];
        #pragma unroll
        for (int m = 0; m < 2; ++m) {
            float sv[2][4];
            #pragma unroll
            for (int jt = 0; jt < 2; ++jt) {
                unsigned int nib = (unsigned int)(bal >> (jt*16 + lg*4)) & 0xFu;
                #pragma unroll
                for (int r = 0; r < 4; ++r) {
                    bool dead = rowm[m] || ((nib >> r) & 1u);
                    float bv = (r == 0) ? bb[m][jt].x : (r == 1) ? bb[m][jt].y
                             : (r == 2) ? bb[m][jt].z : bb[m][jt].w;
                    sv[jt][r] = dead ? -FLT_MAX : fmaf(sac[m][jt][r], temp, bv);
                }
            }
            float pmax = fmaxf(fmaxf(fmaxf(sv[0][0], sv[0][1]), fmaxf(sv[0][2], sv[0][3])),
                               fmaxf(fmaxf(sv[1][0], sv[1][1]), fmaxf(sv[1][2], sv[1][3])));
            pmax = fmaxf(pmax, __shfl_xor(pmax, 16));
            pmax = fmaxf(pmax, __shfl_xor(pmax, 32));
            if (!__all(pmax <= m_r[m] + 8.f)) {      // rare rescale
                float mn = fmaxf(m_r[m], pmax);
                float sc = __expf(m_r[m] - mn);
                m_r[m] = mn;
                l_r[m] *= sc;
                #pragma unroll
                for (int r = 0; r < 4; ++r) {
                    float sq = __shfl(sc, lg*4 + r);
                    #pragma unroll
                    for (int dt = 0; dt < 4; ++dt) oa[m][dt][r] *= sq;
                }
            }
            float rs = 0.f;
            #pragma unroll
            for (int jt = 0; jt < 2; ++jt)
                #pragma unroll
                for (int r = 0; r < 4; ++r) {
                    float pf = __expf(sv[jt][r] - m_r[m]);
                    rs += pf;
                    unsigned short hi = f2bf(pf);
                    pah[m][jt*4 + r] = (short)hi;
                    pal[m][jt*4 + r] = (short)f2bf(pf - bf2f(hi));
                }
            rs += __shfl_xor(rs, 16);
            rs += __shfl_xor(rs, 32);
            l_r[m] += rs;
        }

        // ---- O += P.V ----
        __builtin_amdgcn_s_setprio(1);
        #pragma unroll
        for (int dt = 0; dt < 4; ++dt) {
            short8 vbh = *(const short8*)(&VsH[cur][dt*16 + lm][lg*8]);
            short8 vbl = *(const short8*)(&VsL[cur][dt*16 + lm][lg*8]);
            #pragma unroll
            for (int m = 0; m < 2; ++m) {
                oa[m][dt] = __builtin_amdgcn_mfma_f32_16x16x32_bf16(pah[m], vbh, oa[m][dt], 0, 0, 0);
                oa[m][dt] = __builtin_amdgcn_mfma_f32_16x16x32_bf16(pah[m], vbl, oa[m][dt], 0, 0, 0);
                oa[m][dt] = __builtin_amdgcn_mfma_f32_16x16x32_bf16(pal[m], vbh, oa[m][dt], 0, 0, 0);
            }
        }
        __builtin_amdgcn_s_setprio(0);
        __syncthreads();
        #pragma unroll
        for (int m = 0; m < 2; ++m)
            #pragma unroll
            for (int jt = 0; jt < 2; ++jt) bb[m][jt] = bbn[m][jt];
        mk = mkn;
    }
    #undef A_ISSUE
    #undef STAGE

    // ---- epilogue: f32 partials + (m,l) ----
    #pragma unroll
    for (int m = 0; m < 2; ++m)
        #pragma unroll
        for (int dt = 0; dt < 4; ++dt)
            #pragma unroll
            for (int r = 0; r < 4; ++r)
                Opart[((size_t)(js*16 + bh) * NSEQ + qbase + 16*m + lg*4 + r) * 64
                      + dt*16 + lm] = oa[m][dt][r];
    if (lane < 16) {
        #pragma unroll
        for (int m = 0; m < 2; ++m) {
            size_t mi = ((size_t)(js*16 + bh) * NSEQ + qbase + 16*m + lm) * 2;
            Ml[mi]     = m_r[m];
            Ml[mi + 1] = l_r[m];
        }
    }
}

// ------- merge 3 j-split partials -> AO f32 [M][HD] ----------------------
__global__ __launch_bounds__(256) void merge_kernel(
    const float* __restrict__ Opart, const float* __restrict__ Ml,
    float* __restrict__ AO)
{
    int row = blockIdx.x * 4 + (threadIdx.x >> 6);
    int d = threadIdx.x & 63;
    int bh = row >> 11, n = row & (NSEQ - 1);
    int bq = bh >> 3, hq = bh & 7;
    float mv[3], lv[3];
    float mm = -FLT_MAX;
    #pragma unroll
    for (int p = 0; p < 3; ++p) {
        size_t mi = ((size_t)(p*16 + bh) * NSEQ + n) * 2;
        mv[p] = Ml[mi]; lv[p] = Ml[mi + 1];
        mm = fmaxf(mm, mv[p]);
    }
    float l = 0.f, o = 0.f;
    #pragma unroll
    for (int p = 0; p < 3; ++p) {
        float w = __expf(mv[p] - mm);
        l += lv[p] * w;
        o += Opart[((size_t)(p*16 + bh) * NSEQ + n) * 64 + d] * w;
    }
    o /= l;
    AO[((size_t)(bq * NSEQ + n)) * HD + hq * DIM + d] = o;
}

extern "C" void kernel_launch(void* const* d_in, const int* in_sizes, int n_in,
                              void* d_out, int out_size, void* d_ws, size_t ws_size,
                              hipStream_t stream)
{
    const float*   x        = (const float*)d_in[0];
    const float*   w_qkv    = (const float*)d_in[1];
    const float*   w_out    = (const float*)d_in[2];
    const float*   pos_bias = (const float*)d_in[3];
    const float*   temp     = (const float*)d_in[4];
    const uint8_t* mask     = (const uint8_t*)d_in[5];
    float* out = (float*)d_out;

    const int M = BATCH * NSEQ;                        // 4096
    const size_t NE = (size_t)BATCH * HEADS * NSEQ * DIM;
    char* ws = (char*)d_ws;

    // region 0 (25.2 MB): qkv_lin f32; exactly reused for 3-split f32 Opart
    float* qkv_lin = (float*)ws;
    float* OpartP  = (float*)ws;    // 3*16*2048*64*4 B == M*QKV3*4 B exactly
    size_t off = (size_t)M * QKV3 * 4;
    // region 1 (4.2 MB + 0.79 MB): transposed/split weights + Ml
    ushort_t* WqkvTh = (ushort_t*)(ws + off); off += (size_t)QKV3 * CIN * 2;
    ushort_t* WqkvTl = (ushort_t*)(ws + off); off += (size_t)QKV3 * CIN * 2;
    ushort_t* WoutTh = (ushort_t*)(ws + off); off += (size_t)HD * CIN * 2;
    ushort_t* WoutTl = (ushort_t*)(ws + off); off += (size_t)HD * CIN * 2;
    float*    MlP    = (float*)(ws + off);    off += (size_t)3 * 16 * NSEQ * 2 * 4;
    // region 2 (25.2 MB): phase B: Q/K/Vt; phase C: AO f32 (8 MB, aliases Qh/Ql)
    char* reg2 = ws + off;
    ushort_t* Qh  = (ushort_t*)reg2;
    ushort_t* Ql  = Qh + NE;
    ushort_t* Kh  = Ql + NE;
    ushort_t* Kl  = Kh + NE;
    ushort_t* Vth = Kl + NE;
    ushort_t* Vtl = Vth + NE;
    float* AO = (float*)reg2;       // 8 MB = Qh+Ql slots (dead after attn)

    // 1. weight split+transpose
    split_wT_kernel<<<dim3(QKV3/64, CIN/64), 256, 0, stream>>>(w_qkv, WqkvTh, WqkvTl, CIN, QKV3);
    split_wT_kernel<<<dim3(HD/64,  CIN/64), 256, 0, stream>>>(w_out, WoutTh, WoutTl, CIN, HD);
    // 2. qkv projection (f32 A staged + split in kernel — R3-proven path)
    gemm_split_kernel<<<dim3(QKV3/64, M/128), 256, 0, stream>>>(
        x, WqkvTh, WqkvTl, qkv_lin, M, QKV3, CIN);
    // 3. fused l2norm/split + V transpose
    qkv_prep_kernel<<<dim3(BATCH * HEADS * (NSEQ/64)), 256, 0, stream>>>(
        qkv_lin, Qh, Ql, Kh, Kl, Vth, Vtl);
    // 4. attention (j-split 3; Opart overwrites qkv_lin)
    attn_mfma_kernel<<<dim3(768), 256, 0, stream>>>(
        Qh, Ql, Kh, Kl, Vth, Vtl, pos_bias, temp, mask, OpartP, MlP);
    // 5. merge partials -> AO f32 (overwrites Qh/Ql)
    merge_kernel<<<dim3(M * HEADS / 4), 256, 0, stream>>>(OpartP, MlP, AO);
    // 6. out projection
    gemm_split_kernel<<<dim3(HD/64, M/128), 256, 0, stream>>>(
        AO, WoutTh, WoutTl, out, M, HD, CIN);
}